// Round 4
// baseline (9291.885 us; speedup 1.0000x reference)
//
#include <hip/hip_runtime.h>
#include <hip/hip_bf16.h>

typedef short bf16x8 __attribute__((ext_vector_type(8)));
typedef float f32x4 __attribute__((ext_vector_type(4)));
using bf16 = __hip_bfloat16;

#define MFMA16(a, b, c) __builtin_amdgcn_mfma_f32_16x16x32_bf16(a, b, c, 0, 0, 0)

__device__ __forceinline__ float bf2f(unsigned short u) {
    return __uint_as_float(((unsigned)u) << 16);
}
__device__ __forceinline__ short f2b(float f) {
    __hip_bfloat16 h = __float2bfloat16(f);  // RNE
    return *reinterpret_cast<short*>(&h);
}

// B=4, N=2048, E=1024, H=16, D=64.  Contract (r3 forensics): fp32 in, fp32 out, 2% rel thr.
// GEMM (bt form): C[M,Nc] = A[M,K] * W[Nc,K]^T
// AF32/WF32: operand is fp32 in global (convert to bf16 during LDS staging).
// MODE 2: bf16 scatter into qkv workspace [3][B*H][N][D];  MODE 1: FP32 row-major [M,1024].
template <int MODE, int K, bool AF32, bool WF32>
__global__ __launch_bounds__(256) void gemm_bt_kernel(const void* __restrict__ Ap,
                                                      const void* __restrict__ Wp,
                                                      void* __restrict__ outp) {
    __shared__ bf16 As[64][72];  // pad 72: frag ds_read_b128 lands 2-way (free)
    __shared__ bf16 Ws[64][72];
    const int tid = threadIdx.x;
    const int lane = tid & 63;
    const int w = tid >> 6;
    const int wr = w >> 1, wc = w & 1;
    const int lm = lane & 15, kh = lane >> 4;
    const int m0 = blockIdx.y * 64, n0 = blockIdx.x * 64;
    const int srow = tid >> 2, scol = (tid & 3) * 16;  // staging: 4 threads/row, 16 elems each

    f32x4 acc[2][2] = {};

    for (int k0 = 0; k0 < K; k0 += 64) {
        bf16x8 alo, ahi, wlo, whi;
        if (AF32) {
            const float* Arow = (const float*)Ap + (size_t)(m0 + srow) * K + k0 + scol;
            float4 v0 = *(const float4*)(Arow + 0);
            float4 v1 = *(const float4*)(Arow + 4);
            float4 v2 = *(const float4*)(Arow + 8);
            float4 v3 = *(const float4*)(Arow + 12);
            alo[0] = f2b(v0.x); alo[1] = f2b(v0.y); alo[2] = f2b(v0.z); alo[3] = f2b(v0.w);
            alo[4] = f2b(v1.x); alo[5] = f2b(v1.y); alo[6] = f2b(v1.z); alo[7] = f2b(v1.w);
            ahi[0] = f2b(v2.x); ahi[1] = f2b(v2.y); ahi[2] = f2b(v2.z); ahi[3] = f2b(v2.w);
            ahi[4] = f2b(v3.x); ahi[5] = f2b(v3.y); ahi[6] = f2b(v3.z); ahi[7] = f2b(v3.w);
        } else {
            const bf16* Arow = (const bf16*)Ap + (size_t)(m0 + srow) * K + k0 + scol;
            alo = *(const bf16x8*)(Arow + 0);
            ahi = *(const bf16x8*)(Arow + 8);
        }
        if (WF32) {
            const float* Wrow = (const float*)Wp + (size_t)(n0 + srow) * K + k0 + scol;
            float4 v0 = *(const float4*)(Wrow + 0);
            float4 v1 = *(const float4*)(Wrow + 4);
            float4 v2 = *(const float4*)(Wrow + 8);
            float4 v3 = *(const float4*)(Wrow + 12);
            wlo[0] = f2b(v0.x); wlo[1] = f2b(v0.y); wlo[2] = f2b(v0.z); wlo[3] = f2b(v0.w);
            wlo[4] = f2b(v1.x); wlo[5] = f2b(v1.y); wlo[6] = f2b(v1.z); wlo[7] = f2b(v1.w);
            whi[0] = f2b(v2.x); whi[1] = f2b(v2.y); whi[2] = f2b(v2.z); whi[3] = f2b(v2.w);
            whi[4] = f2b(v3.x); whi[5] = f2b(v3.y); whi[6] = f2b(v3.z); whi[7] = f2b(v3.w);
        } else {
            const bf16* Wrow = (const bf16*)Wp + (size_t)(n0 + srow) * K + k0 + scol;
            wlo = *(const bf16x8*)(Wrow + 0);
            whi = *(const bf16x8*)(Wrow + 8);
        }
        __syncthreads();  // protect prior iteration's frag reads
        *(bf16x8*)&As[srow][scol] = alo;
        *(bf16x8*)&As[srow][scol + 8] = ahi;
        *(bf16x8*)&Ws[srow][scol] = wlo;
        *(bf16x8*)&Ws[srow][scol + 8] = whi;
        __syncthreads();
#pragma unroll
        for (int ks = 0; ks < 2; ks++) {
            bf16x8 af0 = *(const bf16x8*)&As[wr * 32 + lm][ks * 32 + kh * 8];
            bf16x8 af1 = *(const bf16x8*)&As[wr * 32 + 16 + lm][ks * 32 + kh * 8];
            bf16x8 bf0 = *(const bf16x8*)&Ws[wc * 32 + lm][ks * 32 + kh * 8];
            bf16x8 bf1 = *(const bf16x8*)&Ws[wc * 32 + 16 + lm][ks * 32 + kh * 8];
            acc[0][0] = MFMA16(af0, bf0, acc[0][0]);
            acc[0][1] = MFMA16(af0, bf1, acc[0][1]);
            acc[1][0] = MFMA16(af1, bf0, acc[1][0]);
            acc[1][1] = MFMA16(af1, bf1, acc[1][1]);
        }
    }

#pragma unroll
    for (int mt = 0; mt < 2; mt++)
#pragma unroll
        for (int nt = 0; nt < 2; nt++) {
            f32x4 v = acc[mt][nt];
            const int gr0 = m0 + wr * 32 + mt * 16 + kh * 4;
            const int gc = n0 + wc * 32 + nt * 16 + lm;
#pragma unroll
            for (int r = 0; r < 4; r++) {
                const int gr = gr0 + r;
                if (MODE == 2) {
                    bf16* qkv = (bf16*)outp;
                    const int b = gr >> 11, n = gr & 2047;
                    const int which = gc >> 10;  // 0=q 1=k 2=v
                    const int h = (gc >> 6) & 15;
                    const int d = gc & 63;
                    qkv[(size_t)which * 8388608 +
                        ((size_t)((b * 16 + h) * 2048 + n)) * 64 + d] = __float2bfloat16(v[r]);
                } else {
                    float* o = (float*)outp;  // FP32 output (r3 fix: d_out is float*)
                    o[(size_t)gr * 1024 + gc] = v[r];
                }
            }
        }
}

// fp32 flash attention over bf16 Q/K/V: one wave per query row; 4 waves share K/V LDS tiles.
// grid: (N/4, B*H). q held in 64 VGPRs (broadcast once); no +-inf arithmetic anywhere.
__global__ __launch_bounds__(256) void attn_kernel(const unsigned short* __restrict__ Q,
                                                   const unsigned short* __restrict__ K,
                                                   const unsigned short* __restrict__ V,
                                                   bf16* __restrict__ O) {
    __shared__ float Kt[64][64];  // [d][key]
    __shared__ float Vt[64][68];  // [key][d] pad 68: float4 staging writes cover all 32 banks
    const int tid = threadIdx.x;
    const int lane = tid & 63;
    const int wv = tid >> 6;
    const int bh = blockIdx.y;
    const int n = blockIdx.x * 4 + wv;
    const size_t base = (size_t)bh * 2048 * 64;

    const float qown = bf2f(Q[base + (size_t)n * 64 + lane]);
    float q_reg[64];
#pragma unroll
    for (int d = 0; d < 64; d++) q_reg[d] = __shfl(qown, d);

    float m = -1e30f, l = 0.f, o = 0.f;
    const int key = tid & 63, sg = tid >> 6;           // K staging thread map
    const int vrow = tid >> 2, vcol = (tid & 3) * 16;  // V staging thread map

    for (int t = 0; t < 32; t++) {
        __syncthreads();
        const unsigned short* Kp = K + base + t * 4096;
        const unsigned short* Vp = V + base + t * 4096;
#pragma unroll
        for (int i = 0; i < 4; i++) {
            const int d0 = sg * 16 + i * 4;
            ushort4 kv = *(const ushort4*)&Kp[key * 64 + d0];
            Kt[d0 + 0][key] = bf2f(kv.x);
            Kt[d0 + 1][key] = bf2f(kv.y);
            Kt[d0 + 2][key] = bf2f(kv.z);
            Kt[d0 + 3][key] = bf2f(kv.w);
        }
#pragma unroll
        for (int i = 0; i < 2; i++) {
            bf16x8 vv = *(const bf16x8*)&Vp[vrow * 64 + vcol + i * 8];
            float4 f0 = make_float4(bf2f((unsigned short)vv[0]), bf2f((unsigned short)vv[1]),
                                    bf2f((unsigned short)vv[2]), bf2f((unsigned short)vv[3]));
            float4 f1 = make_float4(bf2f((unsigned short)vv[4]), bf2f((unsigned short)vv[5]),
                                    bf2f((unsigned short)vv[6]), bf2f((unsigned short)vv[7]));
            *(float4*)&Vt[vrow][vcol + i * 8] = f0;
            *(float4*)&Vt[vrow][vcol + i * 8 + 4] = f1;
        }
        __syncthreads();

        float s = 0.f;
#pragma unroll
        for (int d = 0; d < 64; d++) s += q_reg[d] * Kt[d][lane];
        s *= 0.125f;  // D^-0.5

        float tmax = s;
#pragma unroll
        for (int off = 32; off > 0; off >>= 1) tmax = fmaxf(tmax, __shfl_xor(tmax, off));
        const float mnew = fmaxf(m, tmax);
        const float alpha = __expf(m - mnew);
        const float p = __expf(s - mnew);
        float ps = p;
#pragma unroll
        for (int off = 32; off > 0; off >>= 1) ps += __shfl_xor(ps, off);
        l = l * alpha + ps;
        o *= alpha;
#pragma unroll
        for (int j = 0; j < 64; j++) o += __shfl(p, j) * Vt[j][lane];
        m = mnew;
    }

    const int b = bh >> 4, h = bh & 15;
    O[((size_t)(b * 2048 + n)) * 1024 + h * 64 + lane] = __float2bfloat16(o / l);
}

extern "C" void kernel_launch(void* const* d_in, const int* in_sizes, int n_in,
                              void* d_out, int out_size, void* d_ws, size_t ws_size,
                              hipStream_t stream) {
    // Contract (established r0-r3): inputs fp32, OUTPUT fp32 (d_out is float*),
    // threshold = 2% of max|ref| -> bf16 MFMA internals are safely in budget.
    const float* x = (const float*)d_in[0];      // [4,2048,1024] fp32
    const float* w_qkv = (const float*)d_in[1];  // [3072,1024] fp32
    const float* w_out = (const float*)d_in[2];  // [1024,1024] fp32
    float* out = (float*)d_out;                  // [4,2048,1024] fp32

    // Workspace: qkv bf16 [3][B*H][N][D] = 50.3 MB, attn bf16 [B,N,E] = 16.8 MB.
    unsigned short* qkvb = (unsigned short*)d_ws;
    unsigned short* attn = qkvb + 3ull * 8388608;

    // 1) QKV projection (fp32 in, bf16 MFMA): [8192,1024] x [3072,1024]^T -> bf16 Q/K/V
    gemm_bt_kernel<2, 1024, true, true>
        <<<dim3(48, 128), 256, 0, stream>>>(x, w_qkv, (void*)qkvb);
    // 2) fp32 flash attention over bf16 Q/K/V -> bf16 attn_out [B,N,E]
    attn_kernel<<<dim3(512, 64), 256, 0, stream>>>(qkvb, qkvb + 8388608, qkvb + 2 * 8388608,
                                                   (bf16*)attn);
    // 3) output projection (bf16 A, fp32 W) -> FP32 out
    gemm_bt_kernel<1, 1024, false, true>
        <<<dim3(16, 128), 256, 0, stream>>>((const void*)attn, w_out, out);
}

// Round 5
// 544.965 us; speedup vs baseline: 17.0504x; 17.0504x over previous
//
#include <hip/hip_runtime.h>
#include <hip/hip_bf16.h>

typedef short bf16x8 __attribute__((ext_vector_type(8)));
typedef float f32x4 __attribute__((ext_vector_type(4)));
using bf16 = __hip_bfloat16;

#define MFMA16(a, b, c) __builtin_amdgcn_mfma_f32_16x16x32_bf16(a, b, c, 0, 0, 0)

__device__ __forceinline__ float bf2f(unsigned short u) {
    return __uint_as_float(((unsigned)u) << 16);
}
__device__ __forceinline__ short f2b(float f) {
    __hip_bfloat16 h = __float2bfloat16(f);  // RNE
    return *reinterpret_cast<short*>(&h);
}

// B=4, N=2048, E=1024, H=16, D=64.  Contract: fp32 in, fp32 out, thr = 2% of max|ref|.
// GEMM (bt form): C[M,Nc] = A[M,K] * W[Nc,K]^T
// AF32/WF32: operand is fp32 in global (convert to bf16 during LDS staging).
// MODE 2: bf16 scatter into qkv workspace [3][B*H][N][D];  MODE 1: FP32 row-major [M,1024].
template <int MODE, int K, bool AF32, bool WF32>
__global__ __launch_bounds__(256) void gemm_bt_kernel(const void* __restrict__ Ap,
                                                      const void* __restrict__ Wp,
                                                      void* __restrict__ outp) {
    __shared__ bf16 As[64][72];
    __shared__ bf16 Ws[64][72];
    const int tid = threadIdx.x;
    const int lane = tid & 63;
    const int w = tid >> 6;
    const int wr = w >> 1, wc = w & 1;
    const int lm = lane & 15, kh = lane >> 4;
    const int m0 = blockIdx.y * 64, n0 = blockIdx.x * 64;
    const int srow = tid >> 2, scol = (tid & 3) * 16;

    f32x4 acc[2][2] = {};

    for (int k0 = 0; k0 < K; k0 += 64) {
        bf16x8 alo, ahi, wlo, whi;
        if (AF32) {
            const float* Arow = (const float*)Ap + (size_t)(m0 + srow) * K + k0 + scol;
            float4 v0 = *(const float4*)(Arow + 0);
            float4 v1 = *(const float4*)(Arow + 4);
            float4 v2 = *(const float4*)(Arow + 8);
            float4 v3 = *(const float4*)(Arow + 12);
            alo[0] = f2b(v0.x); alo[1] = f2b(v0.y); alo[2] = f2b(v0.z); alo[3] = f2b(v0.w);
            alo[4] = f2b(v1.x); alo[5] = f2b(v1.y); alo[6] = f2b(v1.z); alo[7] = f2b(v1.w);
            ahi[0] = f2b(v2.x); ahi[1] = f2b(v2.y); ahi[2] = f2b(v2.z); ahi[3] = f2b(v2.w);
            ahi[4] = f2b(v3.x); ahi[5] = f2b(v3.y); ahi[6] = f2b(v3.z); ahi[7] = f2b(v3.w);
        } else {
            const bf16* Arow = (const bf16*)Ap + (size_t)(m0 + srow) * K + k0 + scol;
            alo = *(const bf16x8*)(Arow + 0);
            ahi = *(const bf16x8*)(Arow + 8);
        }
        if (WF32) {
            const float* Wrow = (const float*)Wp + (size_t)(n0 + srow) * K + k0 + scol;
            float4 v0 = *(const float4*)(Wrow + 0);
            float4 v1 = *(const float4*)(Wrow + 4);
            float4 v2 = *(const float4*)(Wrow + 8);
            float4 v3 = *(const float4*)(Wrow + 12);
            wlo[0] = f2b(v0.x); wlo[1] = f2b(v0.y); wlo[2] = f2b(v0.z); wlo[3] = f2b(v0.w);
            wlo[4] = f2b(v1.x); wlo[5] = f2b(v1.y); wlo[6] = f2b(v1.z); wlo[7] = f2b(v1.w);
            whi[0] = f2b(v2.x); whi[1] = f2b(v2.y); whi[2] = f2b(v2.z); whi[3] = f2b(v2.w);
            whi[4] = f2b(v3.x); whi[5] = f2b(v3.y); whi[6] = f2b(v3.z); whi[7] = f2b(v3.w);
        } else {
            const bf16* Wrow = (const bf16*)Wp + (size_t)(n0 + srow) * K + k0 + scol;
            wlo = *(const bf16x8*)(Wrow + 0);
            whi = *(const bf16x8*)(Wrow + 8);
        }
        __syncthreads();
        *(bf16x8*)&As[srow][scol] = alo;
        *(bf16x8*)&As[srow][scol + 8] = ahi;
        *(bf16x8*)&Ws[srow][scol] = wlo;
        *(bf16x8*)&Ws[srow][scol + 8] = whi;
        __syncthreads();
#pragma unroll
        for (int ks = 0; ks < 2; ks++) {
            bf16x8 af0 = *(const bf16x8*)&As[wr * 32 + lm][ks * 32 + kh * 8];
            bf16x8 af1 = *(const bf16x8*)&As[wr * 32 + 16 + lm][ks * 32 + kh * 8];
            bf16x8 bf0 = *(const bf16x8*)&Ws[wc * 32 + lm][ks * 32 + kh * 8];
            bf16x8 bf1 = *(const bf16x8*)&Ws[wc * 32 + 16 + lm][ks * 32 + kh * 8];
            acc[0][0] = MFMA16(af0, bf0, acc[0][0]);
            acc[0][1] = MFMA16(af0, bf1, acc[0][1]);
            acc[1][0] = MFMA16(af1, bf0, acc[1][0]);
            acc[1][1] = MFMA16(af1, bf1, acc[1][1]);
        }
    }

#pragma unroll
    for (int mt = 0; mt < 2; mt++)
#pragma unroll
        for (int nt = 0; nt < 2; nt++) {
            f32x4 v = acc[mt][nt];
            const int gr0 = m0 + wr * 32 + mt * 16 + kh * 4;
            const int gc = n0 + wc * 32 + nt * 16 + lm;
#pragma unroll
            for (int r = 0; r < 4; r++) {
                const int gr = gr0 + r;
                if (MODE == 2) {
                    bf16* qkv = (bf16*)outp;
                    const int b = gr >> 11, n = gr & 2047;
                    const int which = gc >> 10;  // 0=q 1=k 2=v
                    const int h = (gc >> 6) & 15;
                    const int d = gc & 63;
                    qkv[(size_t)which * 8388608 +
                        ((size_t)((b * 16 + h) * 2048 + n)) * 64 + d] = __float2bfloat16(v[r]);
                } else {
                    float* o = (float*)outp;
                    o[(size_t)gr * 1024 + gc] = v[r];
                }
            }
        }
}

// MFMA flash attention. Block = 4 waves, 128 q-rows; grid (N/128, B*H).
// Per 64-key tile: S=QK^T (16 MFMA/wave), online softmax in C-layout,
// P->A-layout via wave-private LDS round-trip, PV (16 MFMA/wave).
// Kt[key][d], Vt[d][key], Ps[qrow][key], all stride 72 (bank-balanced b128 frags).
__global__ __launch_bounds__(256) void attn_mfma_kernel(const unsigned short* __restrict__ Qg,
                                                        const unsigned short* __restrict__ Kg,
                                                        const unsigned short* __restrict__ Vg,
                                                        unsigned short* __restrict__ O) {
    __shared__ short Kt[64][72];
    __shared__ short Vt[64][72];
    __shared__ short Ps[128][72];
    const int tid = threadIdx.x;
    const int lane = tid & 63;
    const int w = tid >> 6;
    const int lm = lane & 15;
    const int quad = lane >> 4;
    const int bh = blockIdx.y;
    const int n0 = blockIdx.x * 128;
    const size_t base = (size_t)bh * (2048 * 64);

    // Q fragments in registers for all 32 K-tiles: A[m=lm][k=quad*8+j]
    bf16x8 qf[2][2];
#pragma unroll
    for (int mt = 0; mt < 2; mt++)
#pragma unroll
        for (int ks = 0; ks < 2; ks++)
            qf[mt][ks] = *(const bf16x8*)&Qg[base +
                                            (size_t)(n0 + w * 32 + mt * 16 + lm) * 64 +
                                            ks * 32 + quad * 8];

    f32x4 accO[2][4] = {};
    float mrow[2][4], lrow[2][4];
#pragma unroll
    for (int mt = 0; mt < 2; mt++)
#pragma unroll
        for (int r = 0; r < 4; r++) {
            mrow[mt][r] = -1e30f;
            lrow[mt][r] = 0.f;
        }

    const int krow = tid >> 2, kcol = (tid & 3) * 16;    // K staging map
    const int vkey = tid & 63, vd0 = (tid >> 6) * 16;    // V staging map (transpose)

    for (int t = 0; t < 32; t++) {
        const int k0 = t * 64;
        const unsigned short* ksrc = &Kg[base + (size_t)(k0 + krow) * 64 + kcol];
        bf16x8 kv0 = *(const bf16x8*)ksrc;
        bf16x8 kv1 = *(const bf16x8*)(ksrc + 8);
        const unsigned short* vsrc = &Vg[base + (size_t)(k0 + vkey) * 64 + vd0];
        bf16x8 vv0 = *(const bf16x8*)vsrc;
        bf16x8 vv1 = *(const bf16x8*)(vsrc + 8);
        __syncthreads();  // previous tile's frag reads complete
        *(bf16x8*)&Kt[krow][kcol] = kv0;
        *(bf16x8*)&Kt[krow][kcol + 8] = kv1;
#pragma unroll
        for (int j = 0; j < 8; j++) {
            Vt[vd0 + j][vkey] = vv0[j];
            Vt[vd0 + 8 + j][vkey] = vv1[j];
        }
        __syncthreads();

        // S = Q K^T : B[n=key][k=d] from Kt
        bf16x8 kb0[4], kb1[4];
#pragma unroll
        for (int nt = 0; nt < 4; nt++) {
            kb0[nt] = *(const bf16x8*)&Kt[nt * 16 + lm][quad * 8];
            kb1[nt] = *(const bf16x8*)&Kt[nt * 16 + lm][32 + quad * 8];
        }
        f32x4 s[2][4];
#pragma unroll
        for (int mt = 0; mt < 2; mt++)
#pragma unroll
            for (int nt = 0; nt < 4; nt++) {
                f32x4 z = {};
                z = MFMA16(qf[mt][0], kb0[nt], z);
                s[mt][nt] = MFMA16(qf[mt][1], kb1[nt], z);
            }

        // online softmax; C-layout row = quad*4+r (matches per-lane m/l state)
#pragma unroll
        for (int mt = 0; mt < 2; mt++) {
            float sv[4][4];
#pragma unroll
            for (int nt = 0; nt < 4; nt++)
#pragma unroll
                for (int r = 0; r < 4; r++) sv[nt][r] = s[mt][nt][r] * 0.125f;
            float mx[4];
#pragma unroll
            for (int r = 0; r < 4; r++)
                mx[r] = fmaxf(fmaxf(sv[0][r], sv[1][r]), fmaxf(sv[2][r], sv[3][r]));
#pragma unroll
            for (int off = 1; off < 16; off <<= 1)
#pragma unroll
                for (int r = 0; r < 4; r++) mx[r] = fmaxf(mx[r], __shfl_xor(mx[r], off));
            float al[4];
#pragma unroll
            for (int r = 0; r < 4; r++) {
                const float mn = fmaxf(mrow[mt][r], mx[r]);
                al[r] = __expf(mrow[mt][r] - mn);
                mrow[mt][r] = mn;
            }
            float psum[4] = {0.f, 0.f, 0.f, 0.f};
#pragma unroll
            for (int nt = 0; nt < 4; nt++)
#pragma unroll
                for (int r = 0; r < 4; r++) {
                    const float p = __expf(sv[nt][r] - mrow[mt][r]);
                    psum[r] += p;
                    Ps[w * 32 + mt * 16 + quad * 4 + r][nt * 16 + lm] = f2b(p);
                }
#pragma unroll
            for (int off = 1; off < 16; off <<= 1)
#pragma unroll
                for (int r = 0; r < 4; r++) psum[r] += __shfl_xor(psum[r], off);
#pragma unroll
            for (int r = 0; r < 4; r++) lrow[mt][r] = lrow[mt][r] * al[r] + psum[r];
#pragma unroll
            for (int nt = 0; nt < 4; nt++)
#pragma unroll
                for (int r = 0; r < 4; r++) accO[mt][nt][r] *= al[r];
        }

        // PV: A[m=q][k=key] from Ps (wave-private rows -> no barrier), B[n=d][k=key] from Vt
        bf16x8 pa[2][2];
#pragma unroll
        for (int mt = 0; mt < 2; mt++)
#pragma unroll
            for (int ks = 0; ks < 2; ks++)
                pa[mt][ks] = *(const bf16x8*)&Ps[w * 32 + mt * 16 + lm][ks * 32 + quad * 8];
        bf16x8 vb[4][2];
#pragma unroll
        for (int nt = 0; nt < 4; nt++)
#pragma unroll
            for (int ks = 0; ks < 2; ks++)
                vb[nt][ks] = *(const bf16x8*)&Vt[nt * 16 + lm][ks * 32 + quad * 8];
#pragma unroll
        for (int mt = 0; mt < 2; mt++)
#pragma unroll
            for (int nt = 0; nt < 4; nt++) {
                f32x4 a = MFMA16(pa[mt][0], vb[nt][0], accO[mt][nt]);
                accO[mt][nt] = MFMA16(pa[mt][1], vb[nt][1], a);
            }
    }

    const int b = bh >> 4, h = bh & 15;
#pragma unroll
    for (int mt = 0; mt < 2; mt++) {
        float inv[4];
#pragma unroll
        for (int r = 0; r < 4; r++) inv[r] = 1.0f / lrow[mt][r];
#pragma unroll
        for (int nt = 0; nt < 4; nt++)
#pragma unroll
            for (int r = 0; r < 4; r++) {
                const int n = n0 + w * 32 + mt * 16 + quad * 4 + r;
                O[((size_t)(b * 2048 + n)) * 1024 + h * 64 + nt * 16 + lm] =
                    (unsigned short)f2b(accO[mt][nt][r] * inv[r]);
            }
    }
}

extern "C" void kernel_launch(void* const* d_in, const int* in_sizes, int n_in,
                              void* d_out, int out_size, void* d_ws, size_t ws_size,
                              hipStream_t stream) {
    const float* x = (const float*)d_in[0];      // [4,2048,1024] fp32
    const float* w_qkv = (const float*)d_in[1];  // [3072,1024] fp32
    const float* w_out = (const float*)d_in[2];  // [1024,1024] fp32
    float* out = (float*)d_out;                  // [4,2048,1024] fp32

    // Workspace: qkv bf16 [3][B*H][N][D] = 50.3 MB, attn bf16 [B,N,E] = 16.8 MB.
    unsigned short* qkvb = (unsigned short*)d_ws;
    unsigned short* attn = qkvb + 3ull * 8388608;

    // 1) QKV projection (fp32 in, bf16 MFMA) -> bf16 Q/K/V scattered per head
    gemm_bt_kernel<2, 1024, true, true>
        <<<dim3(48, 128), 256, 0, stream>>>(x, w_qkv, (void*)qkvb);
    // 2) MFMA flash attention -> bf16 attn_out [B,N,E]
    attn_mfma_kernel<<<dim3(16, 64), 256, 0, stream>>>(qkvb, qkvb + 8388608,
                                                       qkvb + 2 * 8388608, attn);
    // 3) output projection (bf16 A, fp32 W) -> FP32 out
    gemm_bt_kernel<1, 1024, false, true>
        <<<dim3(16, 128), 256, 0, stream>>>((const void*)attn, w_out, out);
}

// Round 6
// 541.354 us; speedup vs baseline: 17.1642x; 1.0067x over previous
//
#include <hip/hip_runtime.h>
#include <hip/hip_bf16.h>

typedef short bf16x8 __attribute__((ext_vector_type(8)));
typedef float f32x4 __attribute__((ext_vector_type(4)));
using bf16 = __hip_bfloat16;

#define MFMA16(a, b, c) __builtin_amdgcn_mfma_f32_16x16x32_bf16(a, b, c, 0, 0, 0)

__device__ __forceinline__ float bf2f(unsigned short u) {
    return __uint_as_float(((unsigned)u) << 16);
}
__device__ __forceinline__ short f2b(float f) {
    __hip_bfloat16 h = __float2bfloat16(f);  // RNE
    return *reinterpret_cast<short*>(&h);
}

// B=4, N=2048, E=1024, H=16, D=64.  Contract: fp32 in, fp32 out, thr = 2% of max|ref|.
// GEMM (bt form): C[M,Nc] = A[M,K] * W[Nc,K]^T
// MODE 2: bf16 scatter into qkv ws [3][B*H][N][D], Q pre-scaled by 0.125 (exact in bf16).
// MODE 1: FP32 row-major [M,1024].
template <int MODE, int K, bool AF32, bool WF32>
__global__ __launch_bounds__(256) void gemm_bt_kernel(const void* __restrict__ Ap,
                                                      const void* __restrict__ Wp,
                                                      void* __restrict__ outp) {
    __shared__ bf16 As[64][72];
    __shared__ bf16 Ws[64][72];
    const int tid = threadIdx.x;
    const int lane = tid & 63;
    const int w = tid >> 6;
    const int wr = w >> 1, wc = w & 1;
    const int lm = lane & 15, kh = lane >> 4;
    const int m0 = blockIdx.y * 64, n0 = blockIdx.x * 64;
    const int srow = tid >> 2, scol = (tid & 3) * 16;

    f32x4 acc[2][2] = {};

    for (int k0 = 0; k0 < K; k0 += 64) {
        bf16x8 alo, ahi, wlo, whi;
        if (AF32) {
            const float* Arow = (const float*)Ap + (size_t)(m0 + srow) * K + k0 + scol;
            float4 v0 = *(const float4*)(Arow + 0);
            float4 v1 = *(const float4*)(Arow + 4);
            float4 v2 = *(const float4*)(Arow + 8);
            float4 v3 = *(const float4*)(Arow + 12);
            alo[0] = f2b(v0.x); alo[1] = f2b(v0.y); alo[2] = f2b(v0.z); alo[3] = f2b(v0.w);
            alo[4] = f2b(v1.x); alo[5] = f2b(v1.y); alo[6] = f2b(v1.z); alo[7] = f2b(v1.w);
            ahi[0] = f2b(v2.x); ahi[1] = f2b(v2.y); ahi[2] = f2b(v2.z); ahi[3] = f2b(v2.w);
            ahi[4] = f2b(v3.x); ahi[5] = f2b(v3.y); ahi[6] = f2b(v3.z); ahi[7] = f2b(v3.w);
        } else {
            const bf16* Arow = (const bf16*)Ap + (size_t)(m0 + srow) * K + k0 + scol;
            alo = *(const bf16x8*)(Arow + 0);
            ahi = *(const bf16x8*)(Arow + 8);
        }
        if (WF32) {
            const float* Wrow = (const float*)Wp + (size_t)(n0 + srow) * K + k0 + scol;
            float4 v0 = *(const float4*)(Wrow + 0);
            float4 v1 = *(const float4*)(Wrow + 4);
            float4 v2 = *(const float4*)(Wrow + 8);
            float4 v3 = *(const float4*)(Wrow + 12);
            wlo[0] = f2b(v0.x); wlo[1] = f2b(v0.y); wlo[2] = f2b(v0.z); wlo[3] = f2b(v0.w);
            wlo[4] = f2b(v1.x); wlo[5] = f2b(v1.y); wlo[6] = f2b(v1.z); wlo[7] = f2b(v1.w);
            whi[0] = f2b(v2.x); whi[1] = f2b(v2.y); whi[2] = f2b(v2.z); whi[3] = f2b(v2.w);
            whi[4] = f2b(v3.x); whi[5] = f2b(v3.y); whi[6] = f2b(v3.z); whi[7] = f2b(v3.w);
        } else {
            const bf16* Wrow = (const bf16*)Wp + (size_t)(n0 + srow) * K + k0 + scol;
            wlo = *(const bf16x8*)(Wrow + 0);
            whi = *(const bf16x8*)(Wrow + 8);
        }
        __syncthreads();
        *(bf16x8*)&As[srow][scol] = alo;
        *(bf16x8*)&As[srow][scol + 8] = ahi;
        *(bf16x8*)&Ws[srow][scol] = wlo;
        *(bf16x8*)&Ws[srow][scol + 8] = whi;
        __syncthreads();
#pragma unroll
        for (int ks = 0; ks < 2; ks++) {
            bf16x8 af0 = *(const bf16x8*)&As[wr * 32 + lm][ks * 32 + kh * 8];
            bf16x8 af1 = *(const bf16x8*)&As[wr * 32 + 16 + lm][ks * 32 + kh * 8];
            bf16x8 bf0 = *(const bf16x8*)&Ws[wc * 32 + lm][ks * 32 + kh * 8];
            bf16x8 bf1 = *(const bf16x8*)&Ws[wc * 32 + 16 + lm][ks * 32 + kh * 8];
            acc[0][0] = MFMA16(af0, bf0, acc[0][0]);
            acc[0][1] = MFMA16(af0, bf1, acc[0][1]);
            acc[1][0] = MFMA16(af1, bf0, acc[1][0]);
            acc[1][1] = MFMA16(af1, bf1, acc[1][1]);
        }
    }

#pragma unroll
    for (int mt = 0; mt < 2; mt++)
#pragma unroll
        for (int nt = 0; nt < 2; nt++) {
            f32x4 v = acc[mt][nt];
            const int gr0 = m0 + wr * 32 + mt * 16 + kh * 4;
            const int gc = n0 + wc * 32 + nt * 16 + lm;
#pragma unroll
            for (int r = 0; r < 4; r++) {
                const int gr = gr0 + r;
                if (MODE == 2) {
                    bf16* qkv = (bf16*)outp;
                    const int b = gr >> 11, n = gr & 2047;
                    const int which = gc >> 10;  // 0=q 1=k 2=v
                    const int h = (gc >> 6) & 15;
                    const int d = gc & 63;
                    float val = v[r];
                    if (which == 0) val *= 0.125f;  // fold D^-0.5 into Q (exact pow2)
                    qkv[(size_t)which * 8388608 +
                        ((size_t)((b * 16 + h) * 2048 + n)) * 64 + d] = __float2bfloat16(val);
                } else {
                    float* o = (float*)outp;
                    o[(size_t)gr * 1024 + gc] = v[r];
                }
            }
        }
}

// MFMA flash attention v2. Block = 4 waves, 64 q-rows (16/wave); grid (N/64, B*H) = (32,64).
// Double-buffered K/V LDS tiles -> ONE barrier per 64-key tile (write buf^1 overlaps
// compute on buf). Q pre-scaled by 0.125 in the QKV gemm. Softmax in C-layout,
// P->A-layout via wave-private LDS rows (no barrier).
__global__ __launch_bounds__(256) void attn_mfma_kernel(const unsigned short* __restrict__ Qg,
                                                        const unsigned short* __restrict__ Kg,
                                                        const unsigned short* __restrict__ Vg,
                                                        unsigned short* __restrict__ O) {
    __shared__ short Kt[2][64][72];
    __shared__ short Vt[2][64][72];  // [d][key]
    __shared__ short Ps[64][72];
    const int tid = threadIdx.x;
    const int lane = tid & 63;
    const int w = tid >> 6;
    const int lm = lane & 15;
    const int quad = lane >> 4;
    const int bh = blockIdx.y;
    const int n0 = blockIdx.x * 64;
    const size_t base = (size_t)bh * (2048 * 64);

    // Q fragments (A-layout) held in registers all 32 tiles
    bf16x8 qf[2];
#pragma unroll
    for (int ks = 0; ks < 2; ks++)
        qf[ks] = *(const bf16x8*)&Qg[base + (size_t)(n0 + w * 16 + lm) * 64 + ks * 32 + quad * 8];

    f32x4 accO[4] = {};
    float mrow[4], lrow[4];
#pragma unroll
    for (int r = 0; r < 4; r++) {
        mrow[r] = -1e30f;
        lrow[r] = 0.f;
    }

    const int krow = tid >> 2, kcol = (tid & 3) * 16;  // K staging map (4 thr/row)
    const int vkey = tid & 63, vd0 = (tid >> 6) * 16;  // V staging map (transpose)

    // preload tile 0 into buffer 0
    {
        const unsigned short* ksrc = &Kg[base + (size_t)krow * 64 + kcol];
        bf16x8 kv0 = *(const bf16x8*)ksrc;
        bf16x8 kv1 = *(const bf16x8*)(ksrc + 8);
        const unsigned short* vsrc = &Vg[base + (size_t)vkey * 64 + vd0];
        bf16x8 vv0 = *(const bf16x8*)vsrc;
        bf16x8 vv1 = *(const bf16x8*)(vsrc + 8);
        *(bf16x8*)&Kt[0][krow][kcol] = kv0;
        *(bf16x8*)&Kt[0][krow][kcol + 8] = kv1;
#pragma unroll
        for (int j = 0; j < 8; j++) {
            Vt[0][vd0 + j][vkey] = vv0[j];
            Vt[0][vd0 + 8 + j][vkey] = vv1[j];
        }
        __syncthreads();
    }

    for (int t = 0; t < 32; t++) {
        const int cur = t & 1, nxt = cur ^ 1;
        bf16x8 kv0, kv1, vv0, vv1;
        if (t < 31) {  // issue next tile's global loads early; land during compute
            const int k0 = (t + 1) * 64;
            const unsigned short* ksrc = &Kg[base + (size_t)(k0 + krow) * 64 + kcol];
            kv0 = *(const bf16x8*)ksrc;
            kv1 = *(const bf16x8*)(ksrc + 8);
            const unsigned short* vsrc = &Vg[base + (size_t)(k0 + vkey) * 64 + vd0];
            vv0 = *(const bf16x8*)vsrc;
            vv1 = *(const bf16x8*)(vsrc + 8);
        }

        // S = Q K^T (Q pre-scaled): B[n=key][k=d] from Kt[cur]
        bf16x8 kb0[4], kb1[4];
#pragma unroll
        for (int nt = 0; nt < 4; nt++) {
            kb0[nt] = *(const bf16x8*)&Kt[cur][nt * 16 + lm][quad * 8];
            kb1[nt] = *(const bf16x8*)&Kt[cur][nt * 16 + lm][32 + quad * 8];
        }
        f32x4 s[4];
#pragma unroll
        for (int nt = 0; nt < 4; nt++) {
            f32x4 z = {};
            z = MFMA16(qf[0], kb0[nt], z);
            s[nt] = MFMA16(qf[1], kb1[nt], z);
        }

        // online softmax; C-layout row = quad*4+r
        float mx[4];
#pragma unroll
        for (int r = 0; r < 4; r++)
            mx[r] = fmaxf(fmaxf(s[0][r], s[1][r]), fmaxf(s[2][r], s[3][r]));
#pragma unroll
        for (int off = 1; off < 16; off <<= 1)
#pragma unroll
            for (int r = 0; r < 4; r++) mx[r] = fmaxf(mx[r], __shfl_xor(mx[r], off));
        float al[4];
#pragma unroll
        for (int r = 0; r < 4; r++) {
            const float mn = fmaxf(mrow[r], mx[r]);
            al[r] = __expf(mrow[r] - mn);
            mrow[r] = mn;
        }
        float psum[4] = {0.f, 0.f, 0.f, 0.f};
#pragma unroll
        for (int nt = 0; nt < 4; nt++)
#pragma unroll
            for (int r = 0; r < 4; r++) {
                const float p = __expf(s[nt][r] - mrow[r]);
                psum[r] += p;
                Ps[w * 16 + quad * 4 + r][nt * 16 + lm] = f2b(p);
            }
#pragma unroll
        for (int off = 1; off < 16; off <<= 1)
#pragma unroll
            for (int r = 0; r < 4; r++) psum[r] += __shfl_xor(psum[r], off);
#pragma unroll
        for (int r = 0; r < 4; r++) lrow[r] = lrow[r] * al[r] + psum[r];
#pragma unroll
        for (int nt = 0; nt < 4; nt++)
#pragma unroll
            for (int r = 0; r < 4; r++) accO[nt][r] *= al[r];

        // PV: A[m=q][k=key] from wave-private Ps rows; B[n=d][k=key] from Vt[cur]
        bf16x8 pa0 = *(const bf16x8*)&Ps[w * 16 + lm][quad * 8];
        bf16x8 pa1 = *(const bf16x8*)&Ps[w * 16 + lm][32 + quad * 8];
#pragma unroll
        for (int nt = 0; nt < 4; nt++) {
            bf16x8 vb0 = *(const bf16x8*)&Vt[cur][nt * 16 + lm][quad * 8];
            bf16x8 vb1 = *(const bf16x8*)&Vt[cur][nt * 16 + lm][32 + quad * 8];
            f32x4 a = MFMA16(pa0, vb0, accO[nt]);
            accO[nt] = MFMA16(pa1, vb1, a);
        }

        if (t < 31) {  // write NEXT buffer (disjoint from readers) then one barrier
            *(bf16x8*)&Kt[nxt][krow][kcol] = kv0;
            *(bf16x8*)&Kt[nxt][krow][kcol + 8] = kv1;
#pragma unroll
            for (int j = 0; j < 8; j++) {
                Vt[nxt][vd0 + j][vkey] = vv0[j];
                Vt[nxt][vd0 + 8 + j][vkey] = vv1[j];
            }
            __syncthreads();
        }
    }

    const int b = bh >> 4, h = bh & 15;
    float inv[4];
#pragma unroll
    for (int r = 0; r < 4; r++) inv[r] = 1.0f / lrow[r];
#pragma unroll
    for (int nt = 0; nt < 4; nt++)
#pragma unroll
        for (int r = 0; r < 4; r++) {
            const int n = n0 + w * 16 + quad * 4 + r;
            O[((size_t)(b * 2048 + n)) * 1024 + h * 64 + nt * 16 + lm] =
                (unsigned short)f2b(accO[nt][r] * inv[r]);
        }
}

extern "C" void kernel_launch(void* const* d_in, const int* in_sizes, int n_in,
                              void* d_out, int out_size, void* d_ws, size_t ws_size,
                              hipStream_t stream) {
    const float* x = (const float*)d_in[0];      // [4,2048,1024] fp32
    const float* w_qkv = (const float*)d_in[1];  // [3072,1024] fp32
    const float* w_out = (const float*)d_in[2];  // [1024,1024] fp32
    float* out = (float*)d_out;                  // [4,2048,1024] fp32

    // Workspace: qkv bf16 [3][B*H][N][D] = 50.3 MB, attn bf16 [B,N,E] = 16.8 MB.
    unsigned short* qkvb = (unsigned short*)d_ws;
    unsigned short* attn = qkvb + 3ull * 8388608;

    // 1) QKV projection (fp32 in, bf16 MFMA) -> bf16 Q(pre-scaled)/K/V per head
    gemm_bt_kernel<2, 1024, true, true>
        <<<dim3(48, 128), 256, 0, stream>>>(x, w_qkv, (void*)qkvb);
    // 2) MFMA flash attention v2 -> bf16 attn_out [B,N,E]
    attn_mfma_kernel<<<dim3(32, 64), 256, 0, stream>>>(qkvb, qkvb + 8388608,
                                                       qkvb + 2 * 8388608, attn);
    // 3) output projection (bf16 A, fp32 W) -> FP32 out
    gemm_bt_kernel<1, 1024, false, true>
        <<<dim3(16, 128), 256, 0, stream>>>((const void*)attn, w_out, out);
}